// Round 2
// baseline (91.433 us; speedup 1.0000x reference)
//
#include <hip/hip_runtime.h>
#include <hip/hip_bf16.h>
#include <stdint.h>

typedef float  f32x4 __attribute__((ext_vector_type(4)));
typedef _Float16 half8 __attribute__((ext_vector_type(8)));
typedef unsigned int uint32;

#define N1 256
#define N2T 32768
#define BQ 512
#define KT 32

// LDS map (bytes):
//   rowA  [32][528]        @ 0      : Mem tile, pattern-major f16 rows (single buffer)
//   memT  [2][256][64]     @ 16896  : Mem tile transposed, d-major f16 rows, 16B-granule
//                                     XOR-swizzled by (d>>4)&3 (both sides)
//   P     [4 waves][16][80]@ 49664  : per-wave P rows (f16 over 32 patterns)
//   m2    [2][32] f32      @ 54784  : -0.5*||Mem_row||^2 (exact f32)
#define ROWA_PITCH 528
#define MEMT_OFF 16896
#define MEMT_BYTES 16384
#define P_OFF 49664
#define P_WSTRIDE 1280
#define P_PITCH 80
#define M2_OFF 54784
#define LDS_BYTES 55040

union H4 { _Float16 h[4]; unsigned short s[4]; uint2 u2; };

__global__ __launch_bounds__(256, 2) void mhn_flash_k(
    const float* __restrict__ v, const float* __restrict__ Mem,
    float* __restrict__ Opart, float* __restrict__ mpart,
    float* __restrict__ lpart, int CK, int nt)
{
  __shared__ __align__(16) char lds[LDS_BYTES];

  const int tid = threadIdx.x;
  const int w  = tid >> 6;
  const int l  = tid & 63;
  const int lg = l >> 4;      // lane group 0..3
  const int lc = l & 15;      // lane col   0..15

  // XCD swizzle: the 8 q-blocks of one chunk get consecutive s_ -> same XCD
  const int nwg = gridDim.x;
  const int bid = blockIdx.x;
  const int s_  = (bid & 7) * (nwg >> 3) + (bid >> 3);
  const int c   = s_ >> 3;
  const int qb  = s_ & 7;

  // ---- Q (=v block) to registers as f16: lane holds q=lc, d = 8*lg + j + 32*s ----
  half8 v8[8];
  {
    const int qg = qb*64 + (w<<4) + lc;
    const float* vp = v + (size_t)qg*N1 + (lg<<3);
    #pragma unroll
    for (int s=0;s<8;s++){
      float4 a = *(const float4*)(vp + 32*s);
      float4 b = *(const float4*)(vp + 32*s + 4);
      half8 hv;
      hv[0]=(_Float16)a.x; hv[1]=(_Float16)a.y; hv[2]=(_Float16)a.z; hv[3]=(_Float16)a.w;
      hv[4]=(_Float16)b.x; hv[5]=(_Float16)b.y; hv[6]=(_Float16)b.z; hv[7]=(_Float16)b.w;
      v8[s]=hv;
    }
  }

  // staging roles: thread owns pattern pair {2sa, 2sa+1} x d-block sdb*16..+15
  const int sa  = tid >> 4;
  const int sdb = tid & 15;
  float4 x0[4], x1[4];

  auto do_prefetch = [&](int tt){
    const float* rp = Mem + (size_t)(c*CK + tt*KT + 2*sa)*N1 + sdb*16;
    #pragma unroll
    for (int q=0;q<4;q++){
      const int rot = (q + sdb) & 3;           // d-rotation for bank spread
      x0[q] = *(const float4*)(rp + rot*4);
      x1[q] = *(const float4*)(rp + N1 + rot*4);
    }
  };

  auto do_stage = [&](int bw){
    char* ra = lds;                                  // rowA (single)
    char* mt = lds + MEMT_OFF + bw*MEMT_BYTES;       // memT[bw]
    float ssq0 = 0.f, ssq1 = 0.f;
    #pragma unroll
    for (int q=0;q<4;q++){
      const int rot = (q + sdb) & 3;
      float4 a = x0[q], b = x1[q];
      ssq0 += a.x*a.x + a.y*a.y + a.z*a.z + a.w*a.w;
      ssq1 += b.x*b.x + b.y*b.y + b.z*b.z + b.w*b.w;
      H4 ha, hb;
      ha.h[0]=(_Float16)a.x; ha.h[1]=(_Float16)a.y; ha.h[2]=(_Float16)a.z; ha.h[3]=(_Float16)a.w;
      hb.h[0]=(_Float16)b.x; hb.h[1]=(_Float16)b.y; hb.h[2]=(_Float16)b.z; hb.h[3]=(_Float16)b.w;
      // row layout: row p, f16 at byte d*2  (d = sdb*16 + rot*4 + c2)
      *(uint2*)(ra + (2*sa  )*ROWA_PITCH + sdb*32 + rot*8) = ha.u2;
      *(uint2*)(ra + (2*sa+1)*ROWA_PITCH + sdb*32 + rot*8) = hb.u2;
      // transposed: row d (64B = 32 patterns), granule (sa>>2)^((d>>4)&3), dword (sa&3)
      #pragma unroll
      for (int c2=0;c2<4;c2++){
        const uint32 pk = (uint32)ha.s[c2] | ((uint32)hb.s[c2] << 16);
        const int d = sdb*16 + rot*4 + c2;
        *(uint32*)(mt + d*64 + ((((sa>>2) ^ (sdb&3)) << 4) | ((sa&3)*4))) = pk;
      }
    }
    ssq0 += __shfl_xor(ssq0,1); ssq0 += __shfl_xor(ssq0,2); ssq0 += __shfl_xor(ssq0,4); ssq0 += __shfl_xor(ssq0,8);
    ssq1 += __shfl_xor(ssq1,1); ssq1 += __shfl_xor(ssq1,2); ssq1 += __shfl_xor(ssq1,4); ssq1 += __shfl_xor(ssq1,8);
    if (sdb == 0){
      float* m2 = (float*)(lds + M2_OFF + bw*128);
      m2[2*sa]   = -0.5f*ssq0;
      m2[2*sa+1] = -0.5f*ssq1;
    }
  };

  float mrun = -INFINITY, lrun = 0.f;
  f32x4 oacc[16];
  #pragma unroll
  for (int df=0;df<16;df++) oacc[df] = (f32x4){0.f,0.f,0.f,0.f};

  do_prefetch(0);
  do_stage(0);
  __syncthreads();

  for (int tt=0; tt<nt; ++tt){
    const int buf = tt & 1;
    const bool pf = (tt+1 < nt);
    if (pf) do_prefetch(tt+1);

    // ---- S^T = Mem . v : A-frag row = pattern (lc / 16+lc), k-frag = byte lg*16 + s*64 ----
    const char* ra = lds;
    f32x4 sA = {0.f,0.f,0.f,0.f}, sB = {0.f,0.f,0.f,0.f};
    #pragma unroll
    for (int s=0;s<8;s++){
      half8 a0 = *(const half8*)(ra + lc*ROWA_PITCH      + lg*16 + s*64);
      half8 a1 = *(const half8*)(ra + (16+lc)*ROWA_PITCH + lg*16 + s*64);
      sA = __builtin_amdgcn_mfma_f32_16x16x32_f16(a0, v8[s], sA, 0,0,0);
      sB = __builtin_amdgcn_mfma_f32_16x16x32_f16(a1, v8[s], sB, 0,0,0);
    }

    // logits = cross - 0.5*||m||^2 ; C/D: row(pattern) = 4*lg + r, col(q) = lc
    const float* m2p = (const float*)(lds + M2_OFF + buf*128);
    f32x4 m2a = *(const f32x4*)(m2p + lg*4);
    f32x4 m2b = *(const f32x4*)(m2p + 16 + lg*4);
    float sv0=sA[0]+m2a[0], sv1=sA[1]+m2a[1], sv2=sA[2]+m2a[2], sv3=sA[3]+m2a[3];
    float sv4=sB[0]+m2b[0], sv5=sB[1]+m2b[1], sv6=sB[2]+m2b[2], sv7=sB[3]+m2b[3];

    // ---- online softmax over 32 patterns (column q = lc; reduce lanes l^16, l^32) ----
    float tm = fmaxf(fmaxf(fmaxf(sv0,sv1),fmaxf(sv2,sv3)), fmaxf(fmaxf(sv4,sv5),fmaxf(sv6,sv7)));
    tm = fmaxf(tm, __shfl_xor(tm,16));
    tm = fmaxf(tm, __shfl_xor(tm,32));
    if (__any(tm > mrun + 8.0f)){            // defer-max, THR=8 -> P bounded by e^8
      const float nm = fmaxf(mrun, tm);
      const float sc = __expf(mrun - nm);
      lrun *= sc;
      const int scb = __float_as_int(sc);
      // O rows are q = 4*lg + r: pull that column's scale from lane (4*lg+r)
      const float r0 = __int_as_float(__builtin_amdgcn_ds_bpermute((lg*4+0)<<2, scb));
      const float r1 = __int_as_float(__builtin_amdgcn_ds_bpermute((lg*4+1)<<2, scb));
      const float r2 = __int_as_float(__builtin_amdgcn_ds_bpermute((lg*4+2)<<2, scb));
      const float r3 = __int_as_float(__builtin_amdgcn_ds_bpermute((lg*4+3)<<2, scb));
      const f32x4 scv = {r0,r1,r2,r3};
      #pragma unroll
      for (int df=0;df<16;df++) oacc[df] *= scv;
      mrun = nm;
    }
    H4 k0, k1;
    k0.h[0]=(_Float16)__expf(sv0-mrun); k0.h[1]=(_Float16)__expf(sv1-mrun);
    k0.h[2]=(_Float16)__expf(sv2-mrun); k0.h[3]=(_Float16)__expf(sv3-mrun);
    k1.h[0]=(_Float16)__expf(sv4-mrun); k1.h[1]=(_Float16)__expf(sv5-mrun);
    k1.h[2]=(_Float16)__expf(sv6-mrun); k1.h[3]=(_Float16)__expf(sv7-mrun);
    // l-sum from the f16-rounded P (numerator/denominator consistency)
    float ps = ((float)k0.h[0]+(float)k0.h[1]) + ((float)k0.h[2]+(float)k0.h[3])
             + ((float)k1.h[0]+(float)k1.h[1]) + ((float)k1.h[2]+(float)k1.h[3]);
    ps += __shfl_xor(ps,16); ps += __shfl_xor(ps,32);
    lrun += ps;

    __syncthreads();   // all rowA reads done; stage below may overwrite rowA

    // ---- P -> per-wave LDS row q=lc: f16 at byte k*2 (k = pattern) ----
    char* pw = lds + P_OFF + w*P_WSTRIDE + lc*P_PITCH;
    *(uint2*)(pw + lg*8)      = k0.u2;    // patterns 4*lg..+3
    *(uint2*)(pw + 32 + lg*8) = k1.u2;    // patterns 16+4*lg..+3
    const half8 pa = *(const half8*)(lds + P_OFF + w*P_WSTRIDE + lc*P_PITCH + lg*16);

    // ---- PV: O[q][d] += P[q][k] * Mem[k][d]; B-frag k-granule matches A-frag (kappa cancels) ----
    const char* mt = lds + MEMT_OFF + buf*MEMT_BYTES;
    #pragma unroll
    for (int df=0; df<16; df++){
      const half8 bb = *(const half8*)(mt + (df*16 + lc)*64 + ((lg ^ (df&3))<<4));
      oacc[df] = __builtin_amdgcn_mfma_f32_16x16x32_f16(pa, bb, oacc[df], 0,0,0);
    }

    if (pf) do_stage(buf^1);   // writes rowA(tile tt+1), memT[buf^1], m2[buf^1]
    __syncthreads();
  }

  // ---- chunk partials: O f32, m/l f32 ----
  {
    float* Op = Opart + (size_t)c*BQ*N1;
    const int qbase = qb*64 + (w<<4) + lg*4;
    #pragma unroll
    for (int df=0; df<16; df++){
      #pragma unroll
      for (int r=0;r<4;r++){
        Op[(size_t)(qbase+r)*N1 + df*16 + lc] = oacc[df][r];
      }
    }
    if (l < 16){
      mpart[(size_t)c*BQ + qb*64 + (w<<4) + l] = mrun;
      lpart[(size_t)c*BQ + qb*64 + (w<<4) + l] = lrun;
    }
  }
}

__global__ __launch_bounds__(256) void mhn_reduce_k(
    const float* __restrict__ v, const float* __restrict__ mask,
    const float* __restrict__ Opart, const float* __restrict__ mpart,
    const float* __restrict__ lpart, float* __restrict__ out, int nchunk)
{
  const int q = blockIdx.x;
  const int d = threadIdx.x;
  float M = -INFINITY;
  for (int c2=0;c2<nchunk;c2++) M = fmaxf(M, mpart[c2*BQ+q]);
  float L = 0.f, o = 0.f;
  for (int c2=0;c2<nchunk;c2++){
    const float e = __expf(mpart[c2*BQ+q] - M);
    L += lpart[c2*BQ+q]*e;
    o += Opart[((size_t)c2*BQ+q)*N1 + d]*e;
  }
  const float vv = v[q*N1+d], mk = mask[q*N1+d];
  const float ob = o / L;
  out[q*N1+d] = vv + 0.5f*((ob - vv)*mk);
}

extern "C" void kernel_launch(void* const* d_in, const int* in_sizes, int n_in,
                              void* d_out, int out_size, void* d_ws, size_t ws_size,
                              hipStream_t stream)
{
  (void)in_sizes; (void)n_in; (void)out_size;
  const float* v    = (const float*)d_in[0];
  const float* mask = (const float*)d_in[1];
  const float* Mem  = (const float*)d_in[2];
  float* out = (float*)d_out;

  // split-K chunk count, f32 partials; shrink if workspace is small
  const size_t per_chunk = (size_t)BQ*N1*4 + (size_t)BQ*8;
  int nchunk = 64;
  while (nchunk > 1 && (size_t)nchunk*per_chunk > ws_size) nchunk >>= 1;

  char* wsb = (char*)d_ws;
  float* Opart = (float*)wsb;
  float* mpart = (float*)(wsb + (size_t)nchunk*BQ*N1*4);
  float* lpart = mpart + (size_t)nchunk*BQ;

  const int CK = N2T / nchunk;
  const int nt = CK / KT;

  mhn_flash_k<<<dim3(8*nchunk), dim3(256), 0, stream>>>(v, Mem, Opart, mpart, lpart, CK, nt);
  mhn_reduce_k<<<dim3(BQ), dim3(256), 0, stream>>>(v, mask, Opart, mpart, lpart, out, nchunk);
}

// Round 3
// 89.218 us; speedup vs baseline: 1.0248x; 1.0248x over previous
//
#include <hip/hip_runtime.h>
#include <hip/hip_bf16.h>
#include <stdint.h>

typedef float  f32x4 __attribute__((ext_vector_type(4)));
typedef _Float16 half8 __attribute__((ext_vector_type(8)));
typedef unsigned int uint32;

#define N1 256
#define N2T 32768
#define BQ 512
#define KT 32

// LDS map (bytes):
//   rowA  [2][32][528]      @ 0      : Mem tile, pattern-major f16 rows (double buffer)
//   memT  [2][256][64]      @ 33792  : Mem tile transposed, d-major rows; 16B granule g of
//                                      row d stored at position g ^ ((d>>1)&3)
//   P     [4 waves][16][80] @ 66560  : per-wave P rows (f16 over 32 patterns)
//   m2    [2][32] f32       @ 71680  : -0.5*||Mem_row||^2 (exact f32)
#define ROWA_PITCH 528
#define ROWA_BYTES 16896
#define MEMT_OFF 33792
#define MEMT_BYTES 16384
#define P_OFF 66560
#define P_WSTRIDE 1280
#define P_PITCH 80
#define M2_OFF 71680
#define LDS_BYTES 71936

union H4 { _Float16 h[4]; unsigned short s[4]; uint2 u2; };

__global__ __launch_bounds__(256, 2) void mhn_flash_k(
    const float* __restrict__ v, const float* __restrict__ Mem,
    float* __restrict__ Opart, float* __restrict__ mpart,
    float* __restrict__ lpart, int CK, int nt)
{
  __shared__ __align__(16) char lds[LDS_BYTES];

  const int tid = threadIdx.x;
  const int w  = tid >> 6;
  const int l  = tid & 63;
  const int lg = l >> 4;      // lane group 0..3
  const int lc = l & 15;      // lane col   0..15

  // XCD swizzle: the 8 q-blocks of one chunk get consecutive s_ -> same XCD
  const int nwg = gridDim.x;
  const int bid = blockIdx.x;
  const int s_  = (bid & 7) * (nwg >> 3) + (bid >> 3);
  const int c   = s_ >> 3;
  const int qb  = s_ & 7;

  // ---- Q (=v block) to registers as f16: lane holds q=lc, d = 8*lg + j + 32*s ----
  half8 v8[8];
  {
    const int qg = qb*64 + (w<<4) + lc;
    const float* vp = v + (size_t)qg*N1 + (lg<<3);
    #pragma unroll
    for (int s=0;s<8;s++){
      float4 a = *(const float4*)(vp + 32*s);
      float4 b = *(const float4*)(vp + 32*s + 4);
      half8 hv;
      hv[0]=(_Float16)a.x; hv[1]=(_Float16)a.y; hv[2]=(_Float16)a.z; hv[3]=(_Float16)a.w;
      hv[4]=(_Float16)b.x; hv[5]=(_Float16)b.y; hv[6]=(_Float16)b.z; hv[7]=(_Float16)b.w;
      v8[s]=hv;
    }
  }

  // staging roles: thread owns pattern pair {2sa, 2sa+1} x d-block sdb*16..+15
  const int sa  = tid >> 4;
  const int sdb = tid & 15;
  const int hc  = (sdb >> 2) & 3;   // component rotation for memT write bank spread
  float4 x0[4], x1[4];

  auto do_prefetch = [&](int tt){
    const float* rp = Mem + (size_t)(c*CK + tt*KT + 2*sa)*N1 + sdb*16;
    #pragma unroll
    for (int qi=0;qi<4;qi++){
      const int rot = (qi + sdb) & 3;           // d-rotation for bank spread
      x0[qi] = *(const float4*)(rp + rot*4);
      x1[qi] = *(const float4*)(rp + N1 + rot*4);
    }
  };

  auto do_stage = [&](int bw){
    char* ra = lds + bw*ROWA_BYTES;
    char* mt = lds + MEMT_OFF + bw*MEMT_BYTES;
    float ssq0 = 0.f, ssq1 = 0.f;
    #pragma unroll
    for (int qi=0;qi<4;qi++){
      const int rot = (qi + sdb) & 3;
      const float4 a = x0[qi], b = x1[qi];
      ssq0 += a.x*a.x + a.y*a.y + a.z*a.z + a.w*a.w;
      ssq1 += b.x*b.x + b.y*b.y + b.z*b.z + b.w*b.w;
      H4 ha, hb;
      ha.h[0]=(_Float16)a.x; ha.h[1]=(_Float16)a.y; ha.h[2]=(_Float16)a.z; ha.h[3]=(_Float16)a.w;
      hb.h[0]=(_Float16)b.x; hb.h[1]=(_Float16)b.y; hb.h[2]=(_Float16)b.z; hb.h[3]=(_Float16)b.w;
      // rowA rows 2sa, 2sa+1: f16 at byte d*2 (d = sdb*16 + rot*4 + 0..3)
      *(uint2*)(ra + (2*sa  )*ROWA_PITCH + sdb*32 + rot*8) = ha.u2;
      *(uint2*)(ra + (2*sa+1)*ROWA_PITCH + sdb*32 + rot*8) = hb.u2;
      // rotated views: r.s[i] == orig.s[i ^ hc]  (compile-time indexed, no scratch)
      uint32 ax = ha.u2.x, ay = ha.u2.y, bx = hb.u2.x, by = hb.u2.y;
      if (hc & 2){ uint32 t=ax; ax=ay; ay=t; t=bx; bx=by; by=t; }
      if (hc & 1){
        ax=(ax>>16)|(ax<<16); ay=(ay>>16)|(ay<<16);
        bx=(bx>>16)|(bx<<16); by=(by>>16)|(by<<16);
      }
      const uint32 pk[4] = {
        (ax & 0xffffu) | (bx << 16),
        (ax >> 16)     | (by*0u) | (bx & 0xffff0000u),
        (ay & 0xffffu) | (by << 16),
        (ay >> 16)     | (by & 0xffff0000u)
      };
      const int dbase = sdb*16 + rot*4;
      #pragma unroll
      for (int c2s=0;c2s<4;c2s++){
        const int d = dbase + (c2s ^ hc);
        // granule (sa>>2) of row d at position (sa>>2)^((d>>1)&3), dword sa&3
        *(uint32*)(mt + d*64 + ((((sa>>2) ^ ((d>>1)&3)) & 3) << 4) + ((sa&3)<<2)) = pk[c2s];
      }
    }
    ssq0 += __shfl_xor(ssq0,1); ssq0 += __shfl_xor(ssq0,2); ssq0 += __shfl_xor(ssq0,4); ssq0 += __shfl_xor(ssq0,8);
    ssq1 += __shfl_xor(ssq1,1); ssq1 += __shfl_xor(ssq1,2); ssq1 += __shfl_xor(ssq1,4); ssq1 += __shfl_xor(ssq1,8);
    if (sdb == 0){
      float* m2 = (float*)(lds + M2_OFF + bw*128);
      m2[2*sa]   = -0.5f*ssq0;
      m2[2*sa+1] = -0.5f*ssq1;
    }
  };

  float mrun = -INFINITY, lrun = 0.f;
  f32x4 oacc[16];
  #pragma unroll
  for (int df=0;df<16;df++) oacc[df] = (f32x4){0.f,0.f,0.f,0.f};

  do_prefetch(0);
  do_stage(0);
  __syncthreads();

  for (int tt=0; tt<nt; ++tt){
    const int buf = tt & 1;
    const bool pf = (tt+1 < nt);
    if (pf) do_prefetch(tt+1);

    // ---- S^T = Mem . v : A-frag row = pattern (lc / 16+lc), k-slots = byte lg*16 + s*64 ----
    const char* ra = lds + buf*ROWA_BYTES;
    f32x4 sA = {0.f,0.f,0.f,0.f}, sB = {0.f,0.f,0.f,0.f};
    #pragma unroll
    for (int s=0;s<8;s++){
      half8 a0 = *(const half8*)(ra + lc*ROWA_PITCH      + lg*16 + s*64);
      half8 a1 = *(const half8*)(ra + (16+lc)*ROWA_PITCH + lg*16 + s*64);
      sA = __builtin_amdgcn_mfma_f32_16x16x32_f16(a0, v8[s], sA, 0,0,0);
      sB = __builtin_amdgcn_mfma_f32_16x16x32_f16(a1, v8[s], sB, 0,0,0);
    }

    // logits = cross - 0.5*||m||^2 ; C/D: row(pattern) = 4*lg + r, col(q) = lc
    const float* m2p = (const float*)(lds + M2_OFF + buf*128);
    f32x4 m2a = *(const f32x4*)(m2p + lg*4);
    f32x4 m2b = *(const f32x4*)(m2p + 16 + lg*4);
    float sv0=sA[0]+m2a[0], sv1=sA[1]+m2a[1], sv2=sA[2]+m2a[2], sv3=sA[3]+m2a[3];
    float sv4=sB[0]+m2b[0], sv5=sB[1]+m2b[1], sv6=sB[2]+m2b[2], sv7=sB[3]+m2b[3];

    // ---- online softmax over 32 patterns (column q = lc; reduce lanes l^16, l^32) ----
    float tm = fmaxf(fmaxf(fmaxf(sv0,sv1),fmaxf(sv2,sv3)), fmaxf(fmaxf(sv4,sv5),fmaxf(sv6,sv7)));
    tm = fmaxf(tm, __shfl_xor(tm,16));
    tm = fmaxf(tm, __shfl_xor(tm,32));
    if (__any(tm > mrun + 8.0f)){            // defer-max, THR=8 -> P bounded by e^8
      const float nm = fmaxf(mrun, tm);
      const float sc = __expf(mrun - nm);
      lrun *= sc;
      const int scb = __float_as_int(sc);
      // O rows are q = 4*lg + r: pull that column's scale from lane (4*lg+r)
      const float r0 = __int_as_float(__builtin_amdgcn_ds_bpermute((lg*4+0)<<2, scb));
      const float r1 = __int_as_float(__builtin_amdgcn_ds_bpermute((lg*4+1)<<2, scb));
      const float r2 = __int_as_float(__builtin_amdgcn_ds_bpermute((lg*4+2)<<2, scb));
      const float r3 = __int_as_float(__builtin_amdgcn_ds_bpermute((lg*4+3)<<2, scb));
      const f32x4 scv = {r0,r1,r2,r3};
      #pragma unroll
      for (int df=0;df<16;df++) oacc[df] *= scv;
      mrun = nm;
    }
    H4 k0, k1;
    k0.h[0]=(_Float16)__expf(sv0-mrun); k0.h[1]=(_Float16)__expf(sv1-mrun);
    k0.h[2]=(_Float16)__expf(sv2-mrun); k0.h[3]=(_Float16)__expf(sv3-mrun);
    k1.h[0]=(_Float16)__expf(sv4-mrun); k1.h[1]=(_Float16)__expf(sv5-mrun);
    k1.h[2]=(_Float16)__expf(sv6-mrun); k1.h[3]=(_Float16)__expf(sv7-mrun);
    // l-sum from the f16-rounded P (numerator/denominator consistency)
    float ps = ((float)k0.h[0]+(float)k0.h[1]) + ((float)k0.h[2]+(float)k0.h[3])
             + ((float)k1.h[0]+(float)k1.h[1]) + ((float)k1.h[2]+(float)k1.h[3]);
    ps += __shfl_xor(ps,16); ps += __shfl_xor(ps,32);
    lrun += ps;

    // ---- P -> per-wave LDS row q=lc: f16 at byte k*2 (k = pattern) ----
    char* pw = lds + P_OFF + w*P_WSTRIDE + lc*P_PITCH;
    *(uint2*)(pw + lg*8)      = k0.u2;    // patterns 4*lg..+3
    *(uint2*)(pw + 32 + lg*8) = k1.u2;    // patterns 16+4*lg..+3
    const half8 pa = *(const half8*)(lds + P_OFF + w*P_WSTRIDE + lc*P_PITCH + lg*16);

    // ---- PV: O[q][d] += P[q][k] * Mem[k][d]; granule swizzle matches write side ----
    const char* mt = lds + MEMT_OFF + buf*MEMT_BYTES;
    const char* bbase = mt + lc*64 + ((lg ^ ((lc>>1)&3)) << 4);
    #pragma unroll
    for (int df=0; df<16; df++){
      const half8 bb = *(const half8*)(bbase + df*1024);
      oacc[df] = __builtin_amdgcn_mfma_f32_16x16x32_f16(pa, bb, oacc[df], 0,0,0);
    }

    if (pf) do_stage(buf^1);   // writes rowA[buf^1], memT[buf^1], m2[buf^1] only
    __syncthreads();
  }

  // ---- chunk partials: O f32, m/l f32 ----
  {
    float* Op = Opart + (size_t)c*BQ*N1;
    const int qbase = qb*64 + (w<<4) + lg*4;
    #pragma unroll
    for (int df=0; df<16; df++){
      #pragma unroll
      for (int r=0;r<4;r++){
        Op[(size_t)(qbase+r)*N1 + df*16 + lc] = oacc[df][r];
      }
    }
    if (l < 16){
      mpart[(size_t)c*BQ + qb*64 + (w<<4) + l] = mrun;
      lpart[(size_t)c*BQ + qb*64 + (w<<4) + l] = lrun;
    }
  }
}

__global__ __launch_bounds__(256) void mhn_reduce_k(
    const float* __restrict__ v, const float* __restrict__ mask,
    const float* __restrict__ Opart, const float* __restrict__ mpart,
    const float* __restrict__ lpart, float* __restrict__ out, int nchunk)
{
  const int q = blockIdx.x;
  const int d = threadIdx.x;
  float M = -INFINITY;
  #pragma unroll 8
  for (int c2=0;c2<nchunk;c2++) M = fmaxf(M, mpart[c2*BQ+q]);
  float L = 0.f, o = 0.f;
  #pragma unroll 4
  for (int c2=0;c2<nchunk;c2++){
    const float e = __expf(mpart[c2*BQ+q] - M);
    L += lpart[c2*BQ+q]*e;
    o += Opart[((size_t)c2*BQ+q)*N1 + d]*e;
  }
  const float vv = v[q*N1+d], mk = mask[q*N1+d];
  const float ob = o / L;
  out[q*N1+d] = vv + 0.5f*((ob - vv)*mk);
}

extern "C" void kernel_launch(void* const* d_in, const int* in_sizes, int n_in,
                              void* d_out, int out_size, void* d_ws, size_t ws_size,
                              hipStream_t stream)
{
  (void)in_sizes; (void)n_in; (void)out_size;
  const float* v    = (const float*)d_in[0];
  const float* mask = (const float*)d_in[1];
  const float* Mem  = (const float*)d_in[2];
  float* out = (float*)d_out;

  // split-K chunk count, f32 partials; shrink if workspace is small
  const size_t per_chunk = (size_t)BQ*N1*4 + (size_t)BQ*8;
  int nchunk = 64;
  while (nchunk > 1 && (size_t)nchunk*per_chunk > ws_size) nchunk >>= 1;

  char* wsb = (char*)d_ws;
  float* Opart = (float*)wsb;
  float* mpart = (float*)(wsb + (size_t)nchunk*BQ*N1*4);
  float* lpart = mpart + (size_t)nchunk*BQ;

  const int CK = N2T / nchunk;
  const int nt = CK / KT;

  mhn_flash_k<<<dim3(8*nchunk), dim3(256), 0, stream>>>(v, Mem, Opart, mpart, lpart, CK, nt);
  mhn_reduce_k<<<dim3(BQ), dim3(256), 0, stream>>>(v, mask, Opart, mpart, lpart, out, nchunk);
}

// Round 4
// 77.634 us; speedup vs baseline: 1.1777x; 1.1492x over previous
//
#include <hip/hip_runtime.h>
#include <hip/hip_bf16.h>
#include <stdint.h>

typedef float  f32x4 __attribute__((ext_vector_type(4)));
typedef _Float16 half8 __attribute__((ext_vector_type(8)));
typedef unsigned int uint32;

#define N1 256
#define N2T 32768
#define BQ 512
#define KT 32
#define TILE_B 16384

// flash LDS map:
//   rowA [2][16384] @ 0     : 32 pattern rows x 512B, granule g at pos g^(r&7)
//   memT [2][16384] @ 32768 : 256 d rows x 64B, granule g at pos g^((d>>1)&3)
//   P    [4][2560]  @ 65536 : per-wave, 32 q rows x 80B (pats 0..31 f16 at byte 2k)
#define RA_OFF 0
#define MT_OFF 32768
#define P_OFF  65536
#define P_PITCH 80
#define P_WSTR  2560
#define LDS_BYTES 75776

union H4 { _Float16 h[4]; unsigned short s[4]; uint2 u2; };

#define GLD_LDS(gp, lp) __builtin_amdgcn_global_load_lds( \
    (const __attribute__((address_space(1))) void*)(gp), \
    (__attribute__((address_space(3))) void*)(lp), 16, 0, 0)

// ---- preprocess: Mem f32 -> MemA (pattern-major f16, swizzled), MemT (d-major f16,
//      swizzled), m2 = -0.5*||row||^2 (f32). One block per 32-pattern tile. ----
__global__ __launch_bounds__(256) void mhn_prep_k(
    const float* __restrict__ Mem, _Float16* __restrict__ MemA,
    _Float16* __restrict__ MemT, float* __restrict__ m2g)
{
  const int t   = blockIdx.x;
  const int tid = threadIdx.x;
  const int a    = tid >> 4;   // pattern pair {2a, 2a+1} (local)
  const int dblk = tid & 15;   // d block of 16
  const int r0i  = 32*t + 2*a;

  const float* p0 = Mem + (size_t)r0i*N1 + dblk*16;
  const float* p1 = p0 + N1;
  float4 x0[4], x1[4];
  #pragma unroll
  for (int i=0;i<4;i++){ x0[i] = *(const float4*)(p0+4*i); x1[i] = *(const float4*)(p1+4*i); }

  float s0=0.f, s1=0.f;
  H4 h0[4], h1[4];
  #pragma unroll
  for (int i=0;i<4;i++){
    s0 += x0[i].x*x0[i].x + x0[i].y*x0[i].y + x0[i].z*x0[i].z + x0[i].w*x0[i].w;
    s1 += x1[i].x*x1[i].x + x1[i].y*x1[i].y + x1[i].z*x1[i].z + x1[i].w*x1[i].w;
    h0[i].h[0]=(_Float16)x0[i].x; h0[i].h[1]=(_Float16)x0[i].y; h0[i].h[2]=(_Float16)x0[i].z; h0[i].h[3]=(_Float16)x0[i].w;
    h1[i].h[0]=(_Float16)x1[i].x; h1[i].h[1]=(_Float16)x1[i].y; h1[i].h[2]=(_Float16)x1[i].z; h1[i].h[3]=(_Float16)x1[i].w;
  }

  // MemA: row r (512B), d-granule g (d=8g..8g+7) at byte (g^(r&7))*16
  char* bA = (char*)MemA + (size_t)t*TILE_B;
  {
    const int e0 = (2*a)&7, e1 = (2*a+1)&7;
    uint4 wv;
    wv.x=h0[0].u2.x; wv.y=h0[0].u2.y; wv.z=h0[1].u2.x; wv.w=h0[1].u2.y;
    *(uint4*)(bA + (2*a)*512   + (((2*dblk  )^e0)<<4)) = wv;
    wv.x=h0[2].u2.x; wv.y=h0[2].u2.y; wv.z=h0[3].u2.x; wv.w=h0[3].u2.y;
    *(uint4*)(bA + (2*a)*512   + (((2*dblk+1)^e0)<<4)) = wv;
    wv.x=h1[0].u2.x; wv.y=h1[0].u2.y; wv.z=h1[1].u2.x; wv.w=h1[1].u2.y;
    *(uint4*)(bA + (2*a+1)*512 + (((2*dblk  )^e1)<<4)) = wv;
    wv.x=h1[2].u2.x; wv.y=h1[2].u2.y; wv.z=h1[3].u2.x; wv.w=h1[3].u2.y;
    *(uint4*)(bA + (2*a+1)*512 + (((2*dblk+1)^e1)<<4)) = wv;
  }

  // MemT: row d (64B = 32 local patterns), pattern-granule g2=a>>2 at pos g2^((d>>1)&3),
  // dword a&3 (patterns 2a,2a+1 packed lo/hi)
  char* bT = (char*)MemT + (size_t)t*TILE_B;
  #pragma unroll
  for (int i=0;i<4;i++){
    #pragma unroll
    for (int j=0;j<4;j++){
      const int d = dblk*16 + 4*i + j;
      const uint32 pk = (uint32)h0[i].s[j] | ((uint32)h1[i].s[j] << 16);
      *(uint32*)(bT + d*64 + ((((a>>2) ^ ((d>>1)&3)))<<4) + ((a&3)<<2)) = pk;
    }
  }

  s0 += __shfl_xor(s0,1); s0 += __shfl_xor(s0,2); s0 += __shfl_xor(s0,4); s0 += __shfl_xor(s0,8);
  s1 += __shfl_xor(s1,1); s1 += __shfl_xor(s1,2); s1 += __shfl_xor(s1,4); s1 += __shfl_xor(s1,8);
  if (dblk == 0){ m2g[r0i] = -0.5f*s0; m2g[r0i+1] = -0.5f*s1; }
}

// ---- flash kernel: wave owns 32 q rows; DMA staging; dual pre-swizzled layouts ----
__global__ __launch_bounds__(256, 2) void mhn_flash_k(
    const _Float16* __restrict__ MemA, const _Float16* __restrict__ MemT,
    const float* __restrict__ m2g, const float* __restrict__ v,
    __hip_bfloat16* __restrict__ Opart, float* __restrict__ mpart,
    float* __restrict__ lpart, int CK, int nt)
{
  __shared__ __align__(16) char lds[LDS_BYTES];

  const int tid = threadIdx.x;
  const int w  = tid >> 6;
  const int l  = tid & 63;
  const int lg = l >> 4;
  const int lc = l & 15;

  const int nwg = gridDim.x;
  const int bid = blockIdx.x;
  const int s_  = (bid & 7) * (nwg >> 3) + (bid >> 3);
  const int c   = s_ >> 2;
  const int qb  = s_ & 3;

  auto dma = [&](int tt, int bw){
    const size_t off = (size_t)(c*(CK>>5) + tt)*TILE_B + w*4096 + l*16;
    const char* gA = (const char*)MemA + off;
    const char* gT = (const char*)MemT + off;
    char* dA = lds + RA_OFF + bw*TILE_B + w*4096 + l*16;
    char* dT = lds + MT_OFF + bw*TILE_B + w*4096 + l*16;
    #pragma unroll
    for (int i=0;i<4;i++){
      GLD_LDS(gA + i*1024, dA + i*1024);
      GLD_LDS(gT + i*1024, dT + i*1024);
    }
  };

  dma(0, 0);

  // Q: lane holds q = qb*128 + w*32 + lc (v8a) and +16 (v8b); d = lg*8 + j + 32s
  half8 v8a[8], v8b[8];
  {
    const int qg = qb*128 + w*32 + lc;
    const float* vp0 = v + (size_t)qg*N1 + lg*8;
    const float* vp1 = vp0 + 16*N1;
    #pragma unroll
    for (int s=0;s<8;s++){
      float4 a = *(const float4*)(vp0 + 32*s), b = *(const float4*)(vp0 + 32*s + 4);
      half8 hv;
      hv[0]=(_Float16)a.x; hv[1]=(_Float16)a.y; hv[2]=(_Float16)a.z; hv[3]=(_Float16)a.w;
      hv[4]=(_Float16)b.x; hv[5]=(_Float16)b.y; hv[6]=(_Float16)b.z; hv[7]=(_Float16)b.w;
      v8a[s]=hv;
      a = *(const float4*)(vp1 + 32*s); b = *(const float4*)(vp1 + 32*s + 4);
      hv[0]=(_Float16)a.x; hv[1]=(_Float16)a.y; hv[2]=(_Float16)a.z; hv[3]=(_Float16)a.w;
      hv[4]=(_Float16)b.x; hv[5]=(_Float16)b.y; hv[6]=(_Float16)b.z; hv[7]=(_Float16)b.w;
      v8b[s]=hv;
    }
  }

  float mrun0=-INFINITY, mrun1=-INFINITY, lrun0=0.f, lrun1=0.f;
  f32x4 oA[16], oB[16];
  #pragma unroll
  for (int df=0;df<16;df++){ oA[df]=(f32x4){0,0,0,0}; oB[df]=(f32x4){0,0,0,0}; }

  __syncthreads();

  const int x7  = lc & 7;
  const int lcx = (lc >> 1) & 3;

  for (int tt=0; tt<nt; ++tt){
    const int buf = tt & 1;
    const bool pf = (tt+1 < nt);
    if (pf) dma(tt+1, buf^1);

    const float* m2p = m2g + c*CK + tt*KT;
    const f32x4 m2a = *(const f32x4*)(m2p + 4*lg);
    const f32x4 m2b = *(const f32x4*)(m2p + 16 + 4*lg);

    // QK^T: S[pat][q], A rows = patterns from rowA (swizzle-compensated), B = v8
    const char* ra = lds + RA_OFF + buf*TILE_B;
    f32x4 sA0={0,0,0,0}, sB0={0,0,0,0}, sA1={0,0,0,0}, sB1={0,0,0,0};
    #pragma unroll
    for (int s=0;s<8;s++){
      const int g = ((s<<2)|lg) ^ x7;
      const half8 a0 = *(const half8*)(ra + lc*512      + (g<<4));
      const half8 a1 = *(const half8*)(ra + (16+lc)*512 + (g<<4));
      sA0 = __builtin_amdgcn_mfma_f32_16x16x32_f16(a0, v8a[s], sA0, 0,0,0);
      sB0 = __builtin_amdgcn_mfma_f32_16x16x32_f16(a1, v8a[s], sB0, 0,0,0);
      sA1 = __builtin_amdgcn_mfma_f32_16x16x32_f16(a0, v8b[s], sA1, 0,0,0);
      sB1 = __builtin_amdgcn_mfma_f32_16x16x32_f16(a1, v8b[s], sB1, 0,0,0);
    }
    sA0 += m2a; sB0 += m2b; sA1 += m2a; sB1 += m2b;

    // online softmax, two q-columns (lc and 16+lc)
    float tm0 = fmaxf(fmaxf(fmaxf(sA0[0],sA0[1]),fmaxf(sA0[2],sA0[3])),
                      fmaxf(fmaxf(sB0[0],sB0[1]),fmaxf(sB0[2],sB0[3])));
    float tm1 = fmaxf(fmaxf(fmaxf(sA1[0],sA1[1]),fmaxf(sA1[2],sA1[3])),
                      fmaxf(fmaxf(sB1[0],sB1[1]),fmaxf(sB1[2],sB1[3])));
    tm0 = fmaxf(tm0, __shfl_xor(tm0,16)); tm0 = fmaxf(tm0, __shfl_xor(tm0,32));
    tm1 = fmaxf(tm1, __shfl_xor(tm1,16)); tm1 = fmaxf(tm1, __shfl_xor(tm1,32));
    if (__any((tm0 > mrun0 + 8.0f) || (tm1 > mrun1 + 8.0f))){
      const float nm0 = fmaxf(mrun0, tm0), nm1 = fmaxf(mrun1, tm1);
      const float sc0 = __expf(mrun0 - nm0), sc1 = __expf(mrun1 - nm1);
      lrun0 *= sc0; lrun1 *= sc1; mrun0 = nm0; mrun1 = nm1;
      const int b0 = __float_as_int(sc0), b1 = __float_as_int(sc1);
      f32x4 scv0, scv1;
      #pragma unroll
      for (int r2=0;r2<4;r2++){
        scv0[r2] = __int_as_float(__builtin_amdgcn_ds_bpermute((4*lg+r2)<<2, b0));
        scv1[r2] = __int_as_float(__builtin_amdgcn_ds_bpermute((4*lg+r2)<<2, b1));
      }
      #pragma unroll
      for (int df=0;df<16;df++){ oA[df] *= scv0; oB[df] *= scv1; }
    }
    H4 k0,k1,k2,k3;
    k0.h[0]=(_Float16)__expf(sA0[0]-mrun0); k0.h[1]=(_Float16)__expf(sA0[1]-mrun0);
    k0.h[2]=(_Float16)__expf(sA0[2]-mrun0); k0.h[3]=(_Float16)__expf(sA0[3]-mrun0);
    k1.h[0]=(_Float16)__expf(sB0[0]-mrun0); k1.h[1]=(_Float16)__expf(sB0[1]-mrun0);
    k1.h[2]=(_Float16)__expf(sB0[2]-mrun0); k1.h[3]=(_Float16)__expf(sB0[3]-mrun0);
    k2.h[0]=(_Float16)__expf(sA1[0]-mrun1); k2.h[1]=(_Float16)__expf(sA1[1]-mrun1);
    k2.h[2]=(_Float16)__expf(sA1[2]-mrun1); k2.h[3]=(_Float16)__expf(sA1[3]-mrun1);
    k3.h[0]=(_Float16)__expf(sB1[0]-mrun1); k3.h[1]=(_Float16)__expf(sB1[1]-mrun1);
    k3.h[2]=(_Float16)__expf(sB1[2]-mrun1); k3.h[3]=(_Float16)__expf(sB1[3]-mrun1);
    float ps0 = ((float)k0.h[0]+(float)k0.h[1])+((float)k0.h[2]+(float)k0.h[3])
              + ((float)k1.h[0]+(float)k1.h[1])+((float)k1.h[2]+(float)k1.h[3]);
    float ps1 = ((float)k2.h[0]+(float)k2.h[1])+((float)k2.h[2]+(float)k2.h[3])
              + ((float)k3.h[0]+(float)k3.h[1])+((float)k3.h[2]+(float)k3.h[3]);
    ps0 += __shfl_xor(ps0,16); ps0 += __shfl_xor(ps0,32); lrun0 += ps0;
    ps1 += __shfl_xor(ps1,16); ps1 += __shfl_xor(ps1,32); lrun1 += ps1;

    // P rows (wave-private; wave-coherent lgkmcnt ordering, no barrier needed)
    char* pw = lds + P_OFF + w*P_WSTR;
    *(uint2*)(pw + lc*P_PITCH + lg*8)           = k0.u2;
    *(uint2*)(pw + lc*P_PITCH + 32 + lg*8)      = k1.u2;
    *(uint2*)(pw + (16+lc)*P_PITCH + lg*8)      = k2.u2;
    *(uint2*)(pw + (16+lc)*P_PITCH + 32 + lg*8) = k3.u2;
    const half8 pa0 = *(const half8*)(pw + lc*P_PITCH + lg*16);
    const half8 pa1 = *(const half8*)(pw + (16+lc)*P_PITCH + lg*16);

    // PV: O[q][d] += P[q][pat] * Mem[pat][d]; B from memT (swizzle-compensated)
    const char* mtb = lds + MT_OFF + buf*TILE_B + lc*64 + ((lg ^ lcx) << 4);
    #pragma unroll
    for (int df=0; df<16; df++){
      const half8 bb = *(const half8*)(mtb + df*1024);
      oA[df] = __builtin_amdgcn_mfma_f32_16x16x32_f16(pa0, bb, oA[df], 0,0,0);
      oB[df] = __builtin_amdgcn_mfma_f32_16x16x32_f16(pa1, bb, oB[df], 0,0,0);
    }

    __syncthreads();  // drains DMA (vmcnt) + orders LDS buffers for next iter
  }

  // chunk partials
  __hip_bfloat16* Op = Opart + (size_t)c*BQ*N1;
  const int q0 = qb*128 + w*32 + 4*lg;
  #pragma unroll
  for (int df=0; df<16; df++){
    #pragma unroll
    for (int r2=0;r2<4;r2++){
      Op[(size_t)(q0+r2)*N1    + df*16 + lc] = __float2bfloat16(oA[df][r2]);
      Op[(size_t)(q0+16+r2)*N1 + df*16 + lc] = __float2bfloat16(oB[df][r2]);
    }
  }
  if (lg == 0){
    const int qq = qb*128 + w*32 + lc;
    mpart[(size_t)c*BQ + qq]      = mrun0;
    lpart[(size_t)c*BQ + qq]      = lrun0;
    mpart[(size_t)c*BQ + qq + 16] = mrun1;
    lpart[(size_t)c*BQ + qq + 16] = lrun1;
  }
}

__global__ __launch_bounds__(256) void mhn_reduce_k(
    const float* __restrict__ v, const float* __restrict__ mask,
    const __hip_bfloat16* __restrict__ Opart, const float* __restrict__ mpart,
    const float* __restrict__ lpart, float* __restrict__ out, int nchunk)
{
  __shared__ float msh[256], lsh[256];
  const int q = blockIdx.x, tid = threadIdx.x;
  if (tid < nchunk){
    msh[tid] = mpart[(size_t)tid*BQ + q];
    lsh[tid] = lpart[(size_t)tid*BQ + q];
  }
  __syncthreads();
  float M = -INFINITY;
  for (int c2=0;c2<nchunk;c2++) M = fmaxf(M, msh[c2]);
  float L = 0.f, o = 0.f;
  for (int c2=0;c2<nchunk;c2++){
    const float e = __expf(msh[c2] - M);
    L += lsh[c2]*e;
    o += __bfloat162float(Opart[((size_t)c2*BQ + q)*N1 + tid])*e;
  }
  const float vv = v[q*N1+tid], mk = mask[q*N1+tid];
  out[q*N1+tid] = vv + 0.5f*((o/L) - vv)*mk;
}

extern "C" void kernel_launch(void* const* d_in, const int* in_sizes, int n_in,
                              void* d_out, int out_size, void* d_ws, size_t ws_size,
                              hipStream_t stream)
{
  (void)in_sizes; (void)n_in; (void)out_size;
  const float* v    = (const float*)d_in[0];
  const float* mask = (const float*)d_in[1];
  const float* Mem  = (const float*)d_in[2];
  float* out = (float*)d_out;

  // ws layout: MemA f16 (16MB) | MemT f16 (16MB) | m2 f32 (128KB) | Opart bf16 | mpart | lpart
  const size_t fixedB   = (size_t)N2T*N1*2*2 + (size_t)N2T*4;
  const size_t perChunk = (size_t)BQ*N1*2 + (size_t)BQ*8;
  int nchunk = 128;
  while (nchunk > 4 && fixedB + (size_t)nchunk*perChunk > ws_size) nchunk >>= 1;

  char* wsb = (char*)d_ws;
  _Float16* MemA = (_Float16*)wsb;
  _Float16* MemT = (_Float16*)(wsb + (size_t)N2T*N1*2);
  float*    m2g  = (float*)(wsb + (size_t)N2T*N1*4);
  char* pb = wsb + fixedB;
  __hip_bfloat16* Opart = (__hip_bfloat16*)pb;
  float* mpart = (float*)(pb + (size_t)nchunk*BQ*N1*2);
  float* lpart = mpart + (size_t)nchunk*BQ;

  const int CK = N2T / nchunk;
  const int nt = CK / KT;

  mhn_prep_k<<<dim3(N2T/KT), dim3(256), 0, stream>>>(Mem, MemA, MemT, m2g);
  mhn_flash_k<<<dim3(4*nchunk), dim3(256), 0, stream>>>(MemA, MemT, m2g, v, Opart, mpart, lpart, CK, nt);
  mhn_reduce_k<<<dim3(BQ), dim3(256), 0, stream>>>(v, mask, Opart, mpart, lpart, out, nchunk);
}